// Round 3
// baseline (2006.468 us; speedup 1.0000x reference)
//
#include <hip/hip_runtime.h>
#include <hip/hip_bf16.h>

#define B_ 32
#define T_ 64
#define S_ 128
#define H_ 512
#define V_ 32000
#define G_ 2048

typedef __bf16 bf16x8 __attribute__((ext_vector_type(8)));
typedef float  f32x4  __attribute__((ext_vector_type(4)));

// ---------------- embedding lookup (pad_id=0 -> zeros), fp32 + bf16 copies ----
__global__ __launch_bounds__(256) void k_embed(const int* __restrict__ dec,
                                               const float* __restrict__ emb,
                                               float* __restrict__ X,
                                               __hip_bfloat16* __restrict__ Xbf)
{
    int i   = blockIdx.x * 256 + threadIdx.x;   // over 2048*128 float4 groups
    int row = i >> 7;                           // b*T+t
    int c4  = (i & 127) << 2;
    int tok = dec[row];
    float4 v = make_float4(0.f, 0.f, 0.f, 0.f);
    if (tok != 0) v = *(const float4*)(emb + (size_t)tok * H_ + c4);
    *(float4*)(X + (size_t)row * H_ + c4) = v;
    __hip_bfloat16* o = Xbf + (size_t)row * H_ + c4;
    o[0] = __float2bfloat16(v.x); o[1] = __float2bfloat16(v.y);
    o[2] = __float2bfloat16(v.z); o[3] = __float2bfloat16(v.w);
}

// ---------------- generic fp32 -> bf16 convert (vector-4) ----------------
__global__ __launch_bounds__(256) void k_f2bf(const float* __restrict__ in,
                                              __hip_bfloat16* __restrict__ out, int n4)
{
    int i = blockIdx.x * 256 + threadIdx.x;
    if (i >= n4) return;
    float4 v = *(const float4*)(in + (size_t)i * 4);
    __hip_bfloat16* o = out + (size_t)i * 4;
    o[0] = __float2bfloat16(v.x); o[1] = __float2bfloat16(v.y);
    o[2] = __float2bfloat16(v.z); o[3] = __float2bfloat16(v.w);
}

// ---------------- bias combine + state init ----------------
__global__ __launch_bounds__(256) void k_prep(const float* __restrict__ b_ih,
                                              const float* __restrict__ b_hh,
                                              float* __restrict__ bias0, float* __restrict__ bias1,
                                              const float* __restrict__ h0, const float* __restrict__ c0,
                                              float* __restrict__ h0A, float* __restrict__ h1A,
                                              float* __restrict__ c0b, float* __restrict__ c1b)
{
    int i = blockIdx.x * 256 + threadIdx.x;     // 16384 = B*H
    if (i < G_) { bias0[i] = b_ih[i] + b_hh[i]; bias1[i] = b_ih[G_ + i] + b_hh[G_ + i]; }
    h0A[i] = h0[i]; h1A[i] = h0[B_ * H_ + i];
    c0b[i] = c0[i]; c1b[i] = c0[B_ * H_ + i];
}

// ---------------- bf16 NT MFMA GEMM: C[M,ldc] = A[M,K] * B[N,K]^T + bias ----
// 128x128 tile, BK=64, 4 waves (2x2), XOR-swizzled LDS, fp32 output.
__global__ __launch_bounds__(256) void k_gemm_bf16nt(
    const __hip_bfloat16* __restrict__ A,
    const __hip_bfloat16* __restrict__ Bm,
    const float* __restrict__ bias,
    float* __restrict__ C,
    int K, int ldc)
{
    __shared__ __hip_bfloat16 sA[128 * 64];
    __shared__ __hip_bfloat16 sB[128 * 64];
    const int tid  = threadIdx.x;
    const int lane = tid & 63;
    const int wave = tid >> 6;
    const int wr = wave >> 1, wc = wave & 1;
    const int tn = blockIdx.x, tm = blockIdx.y;
    const size_t rowA0 = (size_t)tm * 128, rowB0 = (size_t)tn * 128;

    f32x4 acc[4][4] = {};

    for (int kt = 0; kt < K; kt += 64) {
        uint4 ra[4], rb[4];
#pragma unroll
        for (int i = 0; i < 4; i++) {
            int cid = i * 256 + tid;
            int r = cid >> 3, c = cid & 7;
            ra[i] = *(const uint4*)(A  + (rowA0 + r) * K + kt + c * 8);
            rb[i] = *(const uint4*)(Bm + (rowB0 + r) * K + kt + c * 8);
        }
        __syncthreads();
#pragma unroll
        for (int i = 0; i < 4; i++) {
            int cid = i * 256 + tid;
            int r = cid >> 3, c = cid & 7;
            int cd = c ^ (r & 7);
            *(uint4*)((char*)sA + r * 128 + cd * 16) = ra[i];
            *(uint4*)((char*)sB + r * 128 + cd * 16) = rb[i];
        }
        __syncthreads();
#pragma unroll
        for (int kk = 0; kk < 2; kk++) {
            bf16x8 af[4], bfr[4];
            int kc = kk * 4 + (lane >> 4);
#pragma unroll
            for (int mi = 0; mi < 4; mi++) {
                int r = wr * 64 + mi * 16 + (lane & 15);
                af[mi] = *(const bf16x8*)((const char*)sA + r * 128 + ((kc ^ (r & 7)) << 4));
            }
#pragma unroll
            for (int ni = 0; ni < 4; ni++) {
                int r = wc * 64 + ni * 16 + (lane & 15);
                bfr[ni] = *(const bf16x8*)((const char*)sB + r * 128 + ((kc ^ (r & 7)) << 4));
            }
#pragma unroll
            for (int mi = 0; mi < 4; mi++)
#pragma unroll
                for (int ni = 0; ni < 4; ni++)
                    acc[mi][ni] = __builtin_amdgcn_mfma_f32_16x16x32_bf16(af[mi], bfr[ni], acc[mi][ni], 0, 0, 0);
        }
    }

    const int cl = lane & 15, rg = lane >> 4;
#pragma unroll
    for (int mi = 0; mi < 4; mi++) {
#pragma unroll
        for (int ni = 0; ni < 4; ni++) {
            int col = (int)rowB0 + wc * 64 + ni * 16 + cl;
            float bv = bias[col];
#pragma unroll
            for (int r = 0; r < 4; r++) {
                int row = (int)rowA0 + wr * 64 + mi * 16 + rg * 4 + r;
                C[(size_t)row * ldc + col] = acc[mi][ni][r] + bv;
            }
        }
    }
}

// ---------------- LSTM layer 0 step: gates = XW0_row + h @ Whh0^T ----------
// grid 256 = 64 j-groups x 4 b-groups, 256 thr = 8b x 32 gate-cols
__global__ __launch_bounds__(256) void k_lstm_l0(
    const float* __restrict__ XW0, const float* __restrict__ Whh0,
    const float* __restrict__ X,
    const float* __restrict__ h_prev, float* __restrict__ h_next,
    float* __restrict__ c_buf, float* __restrict__ inp1, int t)
{
    __shared__ float hs[8][516];
    __shared__ float gl[8][33];
    const int tid = threadIdx.x;
    const int jg = blockIdx.x & 63;
    const int bg = blockIdx.x >> 6;
    const int b0 = bg * 8, j0 = jg * 8;
#pragma unroll
    for (int i = 0; i < 4; i++) {
        int cid = i * 256 + tid;
        int bl = cid >> 7, k4 = cid & 127;
        *(float4*)(&hs[bl][k4 * 4]) = *(const float4*)(h_prev + (size_t)(b0 + bl) * H_ + k4 * 4);
    }
    __syncthreads();
    const int bl = tid & 7;
    const int cc = tid >> 3;              // 0..31 = q*8 + jl
    const int q = cc >> 3, jl = cc & 7;
    const int g = q * H_ + j0 + jl;
    const int b = b0 + bl;
    float acc = XW0[(size_t)(b * T_ + t) * G_ + g];
    const float4* wrow = (const float4*)(Whh0 + (size_t)g * H_);
#pragma unroll 4
    for (int k4 = 0; k4 < 128; k4++) {
        float4 w  = wrow[k4];
        float4 h4 = *(const float4*)(&hs[bl][k4 * 4]);
        acc = fmaf(w.x, h4.x, fmaf(w.y, h4.y, fmaf(w.z, h4.z, fmaf(w.w, h4.w, acc))));
    }
    gl[bl][cc] = acc;
    __syncthreads();
    if (tid < 64) {
        int b_l = tid & 7, j_l = tid >> 3;
        float iv = gl[b_l][j_l], fv = gl[b_l][8 + j_l], gv = gl[b_l][16 + j_l], ov = gl[b_l][24 + j_l];
        iv = 1.f / (1.f + expf(-iv)); fv = 1.f / (1.f + expf(-fv)); ov = 1.f / (1.f + expf(-ov));
        gv = tanhf(gv);
        int bb = b0 + b_l, j = j0 + j_l;
        int idx = bb * H_ + j;
        float cp = c_buf[idx];
        float cn = fv * cp + iv * gv;
        float hn = ov * tanhf(cn);
        c_buf[idx]  = cn;
        h_next[idx] = hn;
        inp1[idx]   = hn + X[(size_t)(bb * T_ + t) * H_ + j];
    }
}

// ---------------- LSTM layer 1 step: gates = bias1 + inp1@Wih1^T + h@Whh1^T -
__global__ __launch_bounds__(256) void k_lstm_l1(
    const float* __restrict__ Wih1, const float* __restrict__ Whh1,
    const float* __restrict__ bias1,
    const float* __restrict__ inp1, const float* __restrict__ h_prev,
    float* __restrict__ h_next, float* __restrict__ c_buf,
    float* __restrict__ outs, int t)
{
    __shared__ float is_[8][516];
    __shared__ float hs[8][516];
    __shared__ float gl[8][33];
    const int tid = threadIdx.x;
    const int jg = blockIdx.x & 63;
    const int bg = blockIdx.x >> 6;
    const int b0 = bg * 8, j0 = jg * 8;
#pragma unroll
    for (int i = 0; i < 4; i++) {
        int cid = i * 256 + tid;
        int bl = cid >> 7, k4 = cid & 127;
        *(float4*)(&is_[bl][k4 * 4]) = *(const float4*)(inp1   + (size_t)(b0 + bl) * H_ + k4 * 4);
        *(float4*)(&hs[bl][k4 * 4])  = *(const float4*)(h_prev + (size_t)(b0 + bl) * H_ + k4 * 4);
    }
    __syncthreads();
    const int bl = tid & 7;
    const int cc = tid >> 3;
    const int q = cc >> 3, jl = cc & 7;
    const int g = q * H_ + j0 + jl;
    float acc = bias1[g];
    const float4* wi = (const float4*)(Wih1 + (size_t)g * H_);
    const float4* wh = (const float4*)(Whh1 + (size_t)g * H_);
#pragma unroll 4
    for (int k4 = 0; k4 < 128; k4++) {
        float4 w  = wi[k4];
        float4 x4 = *(const float4*)(&is_[bl][k4 * 4]);
        acc = fmaf(w.x, x4.x, fmaf(w.y, x4.y, fmaf(w.z, x4.z, fmaf(w.w, x4.w, acc))));
    }
#pragma unroll 4
    for (int k4 = 0; k4 < 128; k4++) {
        float4 w  = wh[k4];
        float4 h4 = *(const float4*)(&hs[bl][k4 * 4]);
        acc = fmaf(w.x, h4.x, fmaf(w.y, h4.y, fmaf(w.z, h4.z, fmaf(w.w, h4.w, acc))));
    }
    gl[bl][cc] = acc;
    __syncthreads();
    if (tid < 64) {
        int b_l = tid & 7, j_l = tid >> 3;
        float iv = gl[b_l][j_l], fv = gl[b_l][8 + j_l], gv = gl[b_l][16 + j_l], ov = gl[b_l][24 + j_l];
        iv = 1.f / (1.f + expf(-iv)); fv = 1.f / (1.f + expf(-fv)); ov = 1.f / (1.f + expf(-ov));
        gv = tanhf(gv);
        int bb = b0 + b_l, j = j0 + j_l;
        int idx = bb * H_ + j;
        float cp = c_buf[idx];
        float cn = fv * cp + iv * gv;
        float hn = ov * tanhf(cn);
        c_buf[idx]  = cn;
        h_next[idx] = hn;
        outs[(size_t)(bb * T_ + t) * H_ + j] = hn + is_[b_l][j];
    }
}

// ---------------- attention (all B*T rows at once), writes bf16 A-operand ---
__global__ __launch_bounds__(256) void k_attn(const float* __restrict__ context,
                                              const float* __restrict__ outs,
                                              __hip_bfloat16* __restrict__ ctxbf)
{
    __shared__ float orow[512];
    __shared__ float sc2[128][2];
    __shared__ float la[128];
    const int m = blockIdx.x;         // b*T + t
    const int b = m >> 6;
    const float* ctxb = context + (size_t)b * S_ * H_;
    const int tid = threadIdx.x;
    orow[tid]       = outs[(size_t)m * H_ + tid];
    orow[tid + 256] = outs[(size_t)m * H_ + tid + 256];
    __syncthreads();
    {
        int s = tid >> 1, p = tid & 1;
        const float4* crow = (const float4*)(ctxb + (size_t)s * H_ + p * 256);
        const float4* orp  = (const float4*)(orow + p * 256);
        float acc = 0.f;
#pragma unroll 4
        for (int k = 0; k < 64; k++) {
            float4 cv = crow[k]; float4 ov = orp[k];
            acc = fmaf(cv.x, ov.x, fmaf(cv.y, ov.y, fmaf(cv.z, ov.z, fmaf(cv.w, ov.w, acc))));
        }
        sc2[s][p] = acc;
    }
    __syncthreads();
    if (tid < 64) {
        float a  = sc2[tid][0] + sc2[tid][1];
        float b2 = sc2[tid + 64][0] + sc2[tid + 64][1];
        float mx = fmaxf(a, b2);
#pragma unroll
        for (int off = 32; off >= 1; off >>= 1) mx = fmaxf(mx, __shfl_xor(mx, off, 64));
        float es = expf(a - mx) + expf(b2 - mx);
#pragma unroll
        for (int off = 32; off >= 1; off >>= 1) es += __shfl_xor(es, off, 64);
        float lse = mx + logf(es);
        la[tid]      = a  - lse;
        la[tid + 64] = b2 - lse;
    }
    __syncthreads();
    {
        float a0 = 0.f, a1 = 0.f;
        for (int s2 = 0; s2 < 128; s2++) {
            float w = la[s2];
            a0 = fmaf(ctxb[(size_t)s2 * H_ + tid], w, a0);
            a1 = fmaf(ctxb[(size_t)s2 * H_ + tid + 256], w, a1);
        }
        ctxbf[(size_t)m * H_ + tid]       = __float2bfloat16(a0);
        ctxbf[(size_t)m * H_ + tid + 256] = __float2bfloat16(a1);
    }
}

// ---------------- final state copy ----------------
__global__ __launch_bounds__(256) void k_finalize(const float* __restrict__ h0f,
                                                  const float* __restrict__ h1f,
                                                  const float* __restrict__ c0f,
                                                  const float* __restrict__ c1f,
                                                  float* __restrict__ out)
{
    int i = blockIdx.x * 256 + threadIdx.x;  // 16384
    size_t base = (size_t)B_ * T_ * V_;
    out[base + i]               = h0f[i];
    out[base + B_ * H_ + i]     = h1f[i];
    out[base + 2 * B_ * H_ + i] = c0f[i];
    out[base + 3 * B_ * H_ + i] = c1f[i];
}

extern "C" void kernel_launch(void* const* d_in, const int* in_sizes, int n_in,
                              void* d_out, int out_size, void* d_ws, size_t ws_size,
                              hipStream_t stream)
{
    const float* context = (const float*)d_in[0];
    const int*   dec     = (const int*)d_in[1];
    const float* h0      = (const float*)d_in[2];
    const float* c0      = (const float*)d_in[3];
    const float* emb     = (const float*)d_in[4];
    const float* W_ih    = (const float*)d_in[5];
    const float* W_hh    = (const float*)d_in[6];
    const float* b_ih    = (const float*)d_in[7];
    const float* b_hh    = (const float*)d_in[8];
    const float* Wc      = (const float*)d_in[9];
    const float* bc      = (const float*)d_in[10];
    float* out = (float*)d_out;

    char* ws = (char*)d_ws;
    size_t off = 0;
    auto alloc = [&](size_t bytes) -> char* {
        char* p = ws + off; off += (bytes + 255) & ~(size_t)255; return p;
    };
    float*          X      = (float*)alloc((size_t)B_ * T_ * H_ * 4);
    __hip_bfloat16* Xbf    = (__hip_bfloat16*)alloc((size_t)B_ * T_ * H_ * 2);
    float*          XW0    = (float*)alloc((size_t)B_ * T_ * G_ * 4);
    __hip_bfloat16* Wih0bf = (__hip_bfloat16*)alloc((size_t)G_ * H_ * 2);
    __hip_bfloat16* Wcbf   = (__hip_bfloat16*)alloc((size_t)V_ * H_ * 2);
    float*          bias0  = (float*)alloc(G_ * 4);
    float*          bias1  = (float*)alloc(G_ * 4);
    float*          h0A    = (float*)alloc(B_ * H_ * 4);
    float*          h0B    = (float*)alloc(B_ * H_ * 4);
    float*          h1A    = (float*)alloc(B_ * H_ * 4);
    float*          h1B    = (float*)alloc(B_ * H_ * 4);
    float*          c0b    = (float*)alloc(B_ * H_ * 4);
    float*          c1b    = (float*)alloc(B_ * H_ * 4);
    float*          inp1   = (float*)alloc(B_ * H_ * 4);
    float*          outs   = (float*)alloc((size_t)B_ * T_ * H_ * 4);
    __hip_bfloat16* ctxbf  = (__hip_bfloat16*)alloc((size_t)B_ * T_ * H_ * 2);

    // prep: embedding, converts, biases, initial state
    k_embed<<<(B_ * T_ * H_ / 4) / 256, 256, 0, stream>>>(dec, emb, X, Xbf);
    k_f2bf<<<(G_ * H_ / 4 + 255) / 256, 256, 0, stream>>>(W_ih, Wih0bf, G_ * H_ / 4);
    k_f2bf<<<(V_ * H_ / 4 + 255) / 256, 256, 0, stream>>>(Wc, Wcbf, V_ * H_ / 4);
    k_prep<<<64, 256, 0, stream>>>(b_ih, b_hh, bias0, bias1, h0, c0, h0A, h1A, c0b, c1b);

    // XW0 = X @ W_ih[0]^T + (b_ih0 + b_hh0)   [2048, 2048]
    k_gemm_bf16nt<<<dim3(G_ / 128, (B_ * T_) / 128), 256, 0, stream>>>(Xbf, Wih0bf, bias0, XW0, H_, G_);

    // sequential recurrence: 64 steps x 2 layers
    for (int t = 0; t < T_; ++t) {
        const float* h0r = (t & 1) ? h0B : h0A;
        float*       h0w = (t & 1) ? h0A : h0B;
        const float* h1r = (t & 1) ? h1B : h1A;
        float*       h1w = (t & 1) ? h1A : h1B;
        k_lstm_l0<<<256, 256, 0, stream>>>(XW0, W_hh, X, h0r, h0w, c0b, inp1, t);
        k_lstm_l1<<<256, 256, 0, stream>>>(W_ih + (size_t)G_ * H_, W_hh + (size_t)G_ * H_, bias1,
                                           inp1, h1r, h1w, c1b, outs, t);
    }

    // attention over all (b,t) rows -> bf16 ctx vectors
    k_attn<<<B_ * T_, 256, 0, stream>>>(context, outs, ctxbf);

    // logits = ctx @ Wc^T + bc   [2048, 32000] fp32 straight into d_out
    k_gemm_bf16nt<<<dim3(V_ / 128, (B_ * T_) / 128), 256, 0, stream>>>(ctxbf, Wcbf, bc, out, H_, V_);

    // hT, cT
    k_finalize<<<64, 256, 0, stream>>>(h0A, h1A, c0b, c1b, out);
}

// Round 4
// 1678.611 us; speedup vs baseline: 1.1953x; 1.1953x over previous
//
#include <hip/hip_runtime.h>
#include <hip/hip_bf16.h>

#define B_ 32
#define T_ 64
#define S_ 128
#define H_ 512
#define V_ 32000
#define G_ 2048
#define NBLK 128   // persistent recurrence blocks (<=256 CUs -> co-resident)

typedef __bf16 bf16x8 __attribute__((ext_vector_type(8)));
typedef float  f32x4  __attribute__((ext_vector_type(4)));

// frag-layout element index for a [K=512][B=32] bf16 operand buffer.
// B-frag of mfma_f32_16x16x32_bf16: lane holds Op[n=lane&15][k=(lane>>4)*8+e],
// n-tiles of 16 cols. Layout: [nt][ks=k>>5][lg=(k>>3)&3][col][e=k&7] -> lane
// reads 8 contiguous bf16 (16 B) at frag_idx(kbase, b).
__device__ __forceinline__ int frag_idx(int k, int b) {
    return ((((b >> 4) * 16 + (k >> 5)) * 4 + ((k >> 3) & 3)) * 16 + (b & 15)) * 8 + (k & 7);
}

__device__ __forceinline__ float sigm(float x) { return 1.f / (1.f + expf(-x)); }

// ---------------- embedding (pad_id=0 -> zeros): X fp32 [B*T][H] + xfrag bf16 ----
__global__ __launch_bounds__(256) void k_embed(const int* __restrict__ dec,
                                               const float* __restrict__ emb,
                                               float* __restrict__ X,
                                               __hip_bfloat16* __restrict__ xfrag)
{
    int i   = blockIdx.x * 256 + threadIdx.x;   // 2048 rows x 128 float4 groups
    int row = i >> 7;                           // b*T + t
    int b   = row >> 6, t = row & 63;
    int c4  = (i & 127) << 2;
    int tok = dec[row];
    float4 v = make_float4(0.f, 0.f, 0.f, 0.f);
    if (tok != 0) v = *(const float4*)(emb + (size_t)tok * H_ + c4);
    *(float4*)(X + (size_t)row * H_ + c4) = v;
    __hip_bfloat16* xf = xfrag + (size_t)t * (H_ * B_);
    xf[frag_idx(c4 + 0, b)] = __float2bfloat16(v.x);
    xf[frag_idx(c4 + 1, b)] = __float2bfloat16(v.y);
    xf[frag_idx(c4 + 2, b)] = __float2bfloat16(v.z);
    xf[frag_idx(c4 + 3, b)] = __float2bfloat16(v.w);
}

// ---------------- fp32 -> bf16 convert (Wc) ----------------
__global__ __launch_bounds__(256) void k_f2bf(const float* __restrict__ in,
                                              __hip_bfloat16* __restrict__ out, int n4)
{
    int i = blockIdx.x * 256 + threadIdx.x;
    if (i >= n4) return;
    float4 v = *(const float4*)(in + (size_t)i * 4);
    __hip_bfloat16* o = out + (size_t)i * 4;
    o[0] = __float2bfloat16(v.x); o[1] = __float2bfloat16(v.y);
    o[2] = __float2bfloat16(v.z); o[3] = __float2bfloat16(v.w);
}

// ---------------- persistent fused 2-layer LSTM recurrence ----------------
// 128 blocks x 256 thr. Block i owns j in [4i,4i+4) -> 16 gate rows (4 q x 4 j).
// Weights live in registers as MFMA A-frags (K split across 4 waves).
// Phase p: l0 computes step p (p<=63), l1 computes step p-1 (p>=1); 1 grid
// barrier per phase; h/inp exchanged via bf16 frag buffers (ping-pong).
__global__ __launch_bounds__(256, 1) void k_recur(
    const float* __restrict__ W_ih, const float* __restrict__ W_hh,
    const float* __restrict__ b_ih, const float* __restrict__ b_hh,
    const float* __restrict__ h0_in, const float* __restrict__ c0_in,
    const float* __restrict__ X, const __hip_bfloat16* __restrict__ xfrag,
    __hip_bfloat16* __restrict__ h0f, __hip_bfloat16* __restrict__ h1f,
    __hip_bfloat16* __restrict__ i1f,
    float* __restrict__ outs, float* __restrict__ out_states,
    unsigned* __restrict__ bar)
{
    __shared__ float red[2][4][2][16][17];   // [gateset][wave][ntile][row][col+pad]
    const int tid  = threadIdx.x;
    const int blk  = blockIdx.x;
    const int lane = tid & 63;
    const int w    = tid >> 6;
    const int r    = lane & 15, lg = lane >> 4;

    // ---- load persistent weight A-frags: wf[mat][s], mat={Wih0,Whh0,Wih1,Whh1}
    const int q = r >> 2, jl = r & 3;
    const int g = q * 512 + blk * 4 + jl;
    const float* Wm[4] = { W_ih, W_hh, W_ih + (size_t)G_ * H_, W_hh + (size_t)G_ * H_ };
    bf16x8 wf[4][4];
#pragma unroll
    for (int m = 0; m < 4; m++)
#pragma unroll
        for (int s = 0; s < 4; s++) {
            const float* src = Wm[m] + (size_t)g * H_ + w * 128 + s * 32 + lg * 8;
            union { bf16x8 v; __hip_bfloat16 h[8]; } u;
#pragma unroll
            for (int e = 0; e < 8; e++) u.h[e] = __float2bfloat16(src[e]);
            wf[m][s] = u.v;
        }

    // ---- pointwise-owner state (tid<128): (b, pjl) -> j = blk*4+pjl
    const int b = tid & 31, pjl = (tid >> 5) & 3, pj = blk * 4 + pjl;
    float c0r = 0.f, c1r = 0.f, i1r = 0.f, h0l = 0.f, h1l = 0.f;
    float b0r[4], b1r[4];
    if (tid < 128) {
        c0r = c0_in[b * H_ + pj];
        c1r = c0_in[B_ * H_ + b * H_ + pj];
#pragma unroll
        for (int qq = 0; qq < 4; qq++) {
            b0r[qq] = b_ih[qq * 512 + pj] + b_hh[qq * 512 + pj];
            b1r[qq] = b_ih[G_ + qq * 512 + pj] + b_hh[G_ + qq * 512 + pj];
        }
        // initial frags: phase0 reads h0f[0]; phase1 reads h1f[1]
        h0f[0 * 16384 + frag_idx(pj, b)] = __float2bfloat16(h0_in[b * H_ + pj]);
        h1f[1 * 16384 + frag_idx(pj, b)] = __float2bfloat16(h0_in[B_ * H_ + b * H_ + pj]);
    }

    // ---- grid barrier helper (inline via lambda-less macro pattern)
    auto gbar = [&](int idx) {
        __syncthreads();
        if (tid == 0) {
            __threadfence();   // release: flush writes to coherent point
            __hip_atomic_fetch_add(bar, 1u, __ATOMIC_RELEASE, __HIP_MEMORY_SCOPE_AGENT);
            unsigned tgt = (unsigned)NBLK * (unsigned)(idx + 1);
            while (__hip_atomic_load(bar, __ATOMIC_ACQUIRE, __HIP_MEMORY_SCOPE_AGENT) < tgt)
                __builtin_amdgcn_s_sleep(8);
            __threadfence();   // acquire: invalidate stale caches
        }
        __syncthreads();
    };

    gbar(0);

    for (int p = 0; p <= 64; ++p) {
        // ======== wave matmul section ========
        f32x4 acc0[2] = {}, acc1[2] = {};
        if (p <= 63) {
            const __hip_bfloat16* xb = xfrag + (size_t)p * 16384;
            const __hip_bfloat16* hb = h0f + (size_t)(p & 1) * 16384;
#pragma unroll
            for (int nt = 0; nt < 2; nt++)
#pragma unroll
                for (int s = 0; s < 4; s++) {
                    int ei = frag_idx(w * 128 + s * 32 + lg * 8, nt * 16 + r);
                    bf16x8 bx = *(const bf16x8*)(xb + ei);
                    bf16x8 bh = *(const bf16x8*)(hb + ei);
                    acc0[nt] = __builtin_amdgcn_mfma_f32_16x16x32_bf16(wf[0][s], bx, acc0[nt], 0, 0, 0);
                    acc0[nt] = __builtin_amdgcn_mfma_f32_16x16x32_bf16(wf[1][s], bh, acc0[nt], 0, 0, 0);
                }
        }
        if (p >= 1) {
            const __hip_bfloat16* ib = i1f + (size_t)(p & 1) * 16384;
            const __hip_bfloat16* hb = h1f + (size_t)(p & 1) * 16384;
#pragma unroll
            for (int nt = 0; nt < 2; nt++)
#pragma unroll
                for (int s = 0; s < 4; s++) {
                    int ei = frag_idx(w * 128 + s * 32 + lg * 8, nt * 16 + r);
                    bf16x8 bi = *(const bf16x8*)(ib + ei);
                    bf16x8 bh = *(const bf16x8*)(hb + ei);
                    acc1[nt] = __builtin_amdgcn_mfma_f32_16x16x32_bf16(wf[2][s], bi, acc1[nt], 0, 0, 0);
                    acc1[nt] = __builtin_amdgcn_mfma_f32_16x16x32_bf16(wf[3][s], bh, acc1[nt], 0, 0, 0);
                }
        }
#pragma unroll
        for (int nt = 0; nt < 2; nt++)
#pragma unroll
            for (int rr = 0; rr < 4; rr++) {
                red[0][w][nt][lg * 4 + rr][r] = acc0[nt][rr];
                red[1][w][nt][lg * 4 + rr][r] = acc1[nt][rr];
            }
        __syncthreads();

        // ======== pointwise section (tid<128) ========
        if (tid < 128) {
            const int nt = b >> 4, col = b & 15;
            if (p >= 1) {                        // l1 step t1 = p-1
                int t1 = p - 1;
                float gv[4];
#pragma unroll
                for (int qq = 0; qq < 4; qq++) {
                    float s = b1r[qq];
#pragma unroll
                    for (int ww = 0; ww < 4; ww++) s += red[1][ww][nt][qq * 4 + pjl][col];
                    gv[qq] = s;
                }
                float iv = sigm(gv[0]), fv = sigm(gv[1]);
                float gg = tanhf(gv[2]), ov = sigm(gv[3]);
                c1r = fv * c1r + iv * gg;
                float h1n = ov * tanhf(c1r);
                outs[((size_t)b * T_ + t1) * H_ + pj] = h1n + i1r;
                h1f[(size_t)((p + 1) & 1) * 16384 + frag_idx(pj, b)] = __float2bfloat16(h1n);
                h1l = h1n;
            }
            if (p <= 63) {                       // l0 step t0 = p
                float gv[4];
#pragma unroll
                for (int qq = 0; qq < 4; qq++) {
                    float s = b0r[qq];
#pragma unroll
                    for (int ww = 0; ww < 4; ww++) s += red[0][ww][nt][qq * 4 + pjl][col];
                    gv[qq] = s;
                }
                float iv = sigm(gv[0]), fv = sigm(gv[1]);
                float gg = tanhf(gv[2]), ov = sigm(gv[3]);
                c0r = fv * c0r + iv * gg;
                float h0n = ov * tanhf(c0r);
                float i1n = h0n + X[((size_t)b * T_ + p) * H_ + pj];
                h0f[(size_t)((p + 1) & 1) * 16384 + frag_idx(pj, b)] = __float2bfloat16(h0n);
                i1f[(size_t)((p + 1) & 1) * 16384 + frag_idx(pj, b)] = __float2bfloat16(i1n);
                i1r = i1n;
                h0l = h0n;
            }
        }
        gbar(p + 1);
    }

    // ---- final hT/cT -> out_states = d_out + B*T*V, layout [hT(2,B,H); cT(2,B,H)]
    if (tid < 128) {
        out_states[b * H_ + pj]                 = h0l;
        out_states[B_ * H_ + b * H_ + pj]       = h1l;
        out_states[2 * B_ * H_ + b * H_ + pj]   = c0r;
        out_states[3 * B_ * H_ + b * H_ + pj]   = c1r;
    }
}

// ---------------- bf16 NT MFMA GEMM: C[M,ldc] = A[M,K]*B[N,K]^T + bias ------
// 128x128 tile, BK=64, 4 waves, XOR-swizzled LDS, LDS-staged coalesced
// epilogue (full-line fp32 stores), XCD-chunked 1D block swizzle.
__global__ __launch_bounds__(256) void k_gemm_bf16nt(
    const __hip_bfloat16* __restrict__ A,
    const __hip_bfloat16* __restrict__ Bm,
    const float* __restrict__ bias,
    float* __restrict__ C,
    int K, int ldc, int nM)
{
    __shared__ char smem[64 * 130 * 4];        // 33280 B: sA|sB alias cbuf
    __hip_bfloat16* sA = (__hip_bfloat16*)smem;
    __hip_bfloat16* sB = (__hip_bfloat16*)(smem + 16384);
    float*          cbuf = (float*)smem;       // 64 rows x stride 130 fp32

    const int tid  = threadIdx.x;
    const int lane = tid & 63;
    const int wave = tid >> 6;
    const int wr = wave >> 1, wc = wave & 1;

    // XCD-chunked swizzle: each XCD gets a contiguous chunk; M-fastest inside.
    const int cpx = gridDim.x >> 3;
    const int gid = (blockIdx.x & 7) * cpx + (blockIdx.x >> 3);
    const int tm = gid % nM, tn = gid / nM;
    const size_t rowA0 = (size_t)tm * 128, rowB0 = (size_t)tn * 128;

    f32x4 acc[4][4] = {};

    for (int kt = 0; kt < K; kt += 64) {
        uint4 ra[4], rb[4];
#pragma unroll
        for (int i = 0; i < 4; i++) {
            int cid = i * 256 + tid;
            int rr = cid >> 3, c = cid & 7;
            ra[i] = *(const uint4*)(A  + (rowA0 + rr) * K + kt + c * 8);
            rb[i] = *(const uint4*)(Bm + (rowB0 + rr) * K + kt + c * 8);
        }
        __syncthreads();
#pragma unroll
        for (int i = 0; i < 4; i++) {
            int cid = i * 256 + tid;
            int rr = cid >> 3, c = cid & 7;
            int cd = c ^ (rr & 7);
            *(uint4*)((char*)sA + rr * 128 + cd * 16) = ra[i];
            *(uint4*)((char*)sB + rr * 128 + cd * 16) = rb[i];
        }
        __syncthreads();
#pragma unroll
        for (int kk = 0; kk < 2; kk++) {
            bf16x8 af[4], bfr[4];
            int kc = kk * 4 + (lane >> 4);
#pragma unroll
            for (int mi = 0; mi < 4; mi++) {
                int rr = wr * 64 + mi * 16 + (lane & 15);
                af[mi] = *(const bf16x8*)((const char*)sA + rr * 128 + ((kc ^ (rr & 7)) << 4));
            }
#pragma unroll
            for (int ni = 0; ni < 4; ni++) {
                int rr = wc * 64 + ni * 16 + (lane & 15);
                bfr[ni] = *(const bf16x8*)((const char*)sB + rr * 128 + ((kc ^ (rr & 7)) << 4));
            }
#pragma unroll
            for (int mi = 0; mi < 4; mi++)
#pragma unroll
                for (int ni = 0; ni < 4; ni++)
                    acc[mi][ni] = __builtin_amdgcn_mfma_f32_16x16x32_bf16(af[mi], bfr[ni], acc[mi][ni], 0, 0, 0);
        }
    }

    // ---- epilogue: stage each 64-row half in LDS, write full 128B lines ----
    const int cl = lane & 15, rg = lane >> 4;
#pragma unroll
    for (int half = 0; half < 2; half++) {
        __syncthreads();
        if (wr == half) {
#pragma unroll
            for (int mi = 0; mi < 4; mi++)
#pragma unroll
                for (int ni = 0; ni < 4; ni++)
#pragma unroll
                    for (int rr = 0; rr < 4; rr++)
                        cbuf[(mi * 16 + rg * 4 + rr) * 130 + wc * 64 + ni * 16 + cl] = acc[mi][ni][rr];
        }
        __syncthreads();
        int c4 = (tid & 31) * 4;
        float4 bb = *(const float4*)(bias + rowB0 + c4);
#pragma unroll
        for (int it = 0; it < 8; it++) {
            int rrow = it * 8 + (tid >> 5);
            float4 vv = *(float4*)(cbuf + rrow * 130 + c4);
            vv.x += bb.x; vv.y += bb.y; vv.z += bb.z; vv.w += bb.w;
            *(float4*)(C + (size_t)(rowA0 + half * 64 + rrow) * ldc + rowB0 + c4) = vv;
        }
    }
}

// ---------------- attention (all B*T rows), writes bf16 A-operand ----------
__global__ __launch_bounds__(256) void k_attn(const float* __restrict__ context,
                                              const float* __restrict__ outs,
                                              __hip_bfloat16* __restrict__ ctxbf)
{
    __shared__ float orow[512];
    __shared__ float sc2[128][2];
    __shared__ float la[128];
    const int m = blockIdx.x;         // b*T + t
    const int b = m >> 6;
    const float* ctxb = context + (size_t)b * S_ * H_;
    const int tid = threadIdx.x;
    orow[tid]       = outs[(size_t)m * H_ + tid];
    orow[tid + 256] = outs[(size_t)m * H_ + tid + 256];
    __syncthreads();
    {
        int s = tid >> 1, p = tid & 1;
        const float4* crow = (const float4*)(ctxb + (size_t)s * H_ + p * 256);
        const float4* orp  = (const float4*)(orow + p * 256);
        float acc = 0.f;
#pragma unroll 4
        for (int k = 0; k < 64; k++) {
            float4 cv = crow[k]; float4 ov = orp[k];
            acc = fmaf(cv.x, ov.x, fmaf(cv.y, ov.y, fmaf(cv.z, ov.z, fmaf(cv.w, ov.w, acc))));
        }
        sc2[s][p] = acc;
    }
    __syncthreads();
    if (tid < 64) {
        float a  = sc2[tid][0] + sc2[tid][1];
        float b2 = sc2[tid + 64][0] + sc2[tid + 64][1];
        float mx = fmaxf(a, b2);
#pragma unroll
        for (int off = 32; off >= 1; off >>= 1) mx = fmaxf(mx, __shfl_xor(mx, off, 64));
        float es = expf(a - mx) + expf(b2 - mx);
#pragma unroll
        for (int off = 32; off >= 1; off >>= 1) es += __shfl_xor(es, off, 64);
        float lse = mx + logf(es);
        la[tid]      = a  - lse;
        la[tid + 64] = b2 - lse;
    }
    __syncthreads();
    {
        float a0 = 0.f, a1 = 0.f;
        for (int s2 = 0; s2 < 128; s2++) {
            float w = la[s2];
            a0 = fmaf(ctxb[(size_t)s2 * H_ + tid], w, a0);
            a1 = fmaf(ctxb[(size_t)s2 * H_ + tid + 256], w, a1);
        }
        ctxbf[(size_t)m * H_ + tid]       = __float2bfloat16(a0);
        ctxbf[(size_t)m * H_ + tid + 256] = __float2bfloat16(a1);
    }
}

extern "C" void kernel_launch(void* const* d_in, const int* in_sizes, int n_in,
                              void* d_out, int out_size, void* d_ws, size_t ws_size,
                              hipStream_t stream)
{
    const float* context = (const float*)d_in[0];
    const int*   dec     = (const int*)d_in[1];
    const float* h0      = (const float*)d_in[2];
    const float* c0      = (const float*)d_in[3];
    const float* emb     = (const float*)d_in[4];
    const float* W_ih    = (const float*)d_in[5];
    const float* W_hh    = (const float*)d_in[6];
    const float* b_ih    = (const float*)d_in[7];
    const float* b_hh    = (const float*)d_in[8];
    const float* Wc      = (const float*)d_in[9];
    const float* bc      = (const float*)d_in[10];
    float* out = (float*)d_out;

    char* ws = (char*)d_ws;
    size_t off = 0;
    auto alloc = [&](size_t bytes) -> char* {
        char* p = ws + off; off += (bytes + 255) & ~(size_t)255; return p;
    };
    float*          X      = (float*)alloc((size_t)B_ * T_ * H_ * 4);
    __hip_bfloat16* xfrag  = (__hip_bfloat16*)alloc((size_t)T_ * H_ * B_ * 2);
    __hip_bfloat16* h0f    = (__hip_bfloat16*)alloc(2 * (size_t)H_ * B_ * 2);
    __hip_bfloat16* h1f    = (__hip_bfloat16*)alloc(2 * (size_t)H_ * B_ * 2);
    __hip_bfloat16* i1f    = (__hip_bfloat16*)alloc(2 * (size_t)H_ * B_ * 2);
    float*          outs   = (float*)alloc((size_t)B_ * T_ * H_ * 4);
    __hip_bfloat16* ctxbf  = (__hip_bfloat16*)alloc((size_t)B_ * T_ * H_ * 2);
    __hip_bfloat16* Wcbf   = (__hip_bfloat16*)alloc((size_t)V_ * H_ * 2);
    unsigned*       bar    = (unsigned*)alloc(256);

    // barrier counter must start at 0 (ws is poisoned 0xAA each call)
    hipMemsetAsync(bar, 0, 256, stream);

    // prep: embedding (+frag layout) and Wc convert
    k_embed<<<(B_ * T_ * H_ / 4) / 256, 256, 0, stream>>>(dec, emb, X, xfrag);
    k_f2bf<<<(V_ * H_ / 4 + 255) / 256, 256, 0, stream>>>(Wc, Wcbf, V_ * H_ / 4);

    // persistent fused recurrence (all 64 steps, both layers, hT/cT epilogue)
    k_recur<<<NBLK, 256, 0, stream>>>(W_ih, W_hh, b_ih, b_hh, h0, c0,
                                      X, xfrag, h0f, h1f, i1f,
                                      outs, out + (size_t)B_ * T_ * V_, bar);

    // attention over all (b,t) rows -> bf16 ctx vectors
    k_attn<<<B_ * T_, 256, 0, stream>>>(context, outs, ctxbf);

    // logits = ctx @ Wc^T + bc  [2048, 32000] fp32 into d_out (XCD-swizzled)
    k_gemm_bf16nt<<<(V_ / 128) * ((B_ * T_) / 128), 256, 0, stream>>>(
        ctxbf, Wcbf, bc, out, H_, V_, (B_ * T_) / 128);
}

// Round 5
// 1357.709 us; speedup vs baseline: 1.4778x; 1.2364x over previous
//
#include <hip/hip_runtime.h>
#include <hip/hip_bf16.h>

#define B_ 32
#define T_ 64
#define S_ 128
#define H_ 512
#define V_ 32000
#define G_ 2048
#define NBLK 128   // persistent recurrence blocks (<=256 CUs -> co-resident)

typedef __bf16 bf16x8 __attribute__((ext_vector_type(8)));
typedef float  f32x4  __attribute__((ext_vector_type(4)));

__device__ __forceinline__ float sigm(float x) { return 1.f / (1.f + expf(-x)); }
__device__ __forceinline__ unsigned short bf16b(float x) {
    union { __hip_bfloat16 h; unsigned short u; } c; c.h = __float2bfloat16(x); return c.u;
}

// ---------------- embedding (pad_id=0 -> zeros) -> Xbf [B*T][H] bf16 --------
__global__ __launch_bounds__(256) void k_embed(const int* __restrict__ dec,
                                               const float* __restrict__ emb,
                                               __hip_bfloat16* __restrict__ Xbf)
{
    int i   = blockIdx.x * 256 + threadIdx.x;   // 2048 rows x 128 float4 groups
    int row = i >> 7;
    int c4  = (i & 127) << 2;
    int tok = dec[row];
    float4 v = make_float4(0.f, 0.f, 0.f, 0.f);
    if (tok != 0) v = *(const float4*)(emb + (size_t)tok * H_ + c4);
    __hip_bfloat16* o = Xbf + (size_t)row * H_ + c4;
    o[0] = __float2bfloat16(v.x); o[1] = __float2bfloat16(v.y);
    o[2] = __float2bfloat16(v.z); o[3] = __float2bfloat16(v.w);
}

// ---------------- fp32 -> bf16 convert ----------------
__global__ __launch_bounds__(256) void k_f2bf(const float* __restrict__ in,
                                              __hip_bfloat16* __restrict__ out, int n4)
{
    int i = blockIdx.x * 256 + threadIdx.x;
    if (i >= n4) return;
    float4 v = *(const float4*)(in + (size_t)i * 4);
    __hip_bfloat16* o = out + (size_t)i * 4;
    o[0] = __float2bfloat16(v.x); o[1] = __float2bfloat16(v.y);
    o[2] = __float2bfloat16(v.z); o[3] = __float2bfloat16(v.w);
}

// ---------------- combined biases ----------------
__global__ __launch_bounds__(256) void k_prep(const float* __restrict__ b_ih,
                                              const float* __restrict__ b_hh,
                                              float* __restrict__ bias0,
                                              float* __restrict__ bias1)
{
    int i = blockIdx.x * 256 + threadIdx.x;  // 2048
    bias0[i] = b_ih[i] + b_hh[i];
    bias1[i] = b_ih[G_ + i] + b_hh[G_ + i];
}

// ---------------- persistent fused 2-layer LSTM recurrence (v2) -------------
// 128 blocks x 256 thr; block owns 4 hidden dims (16 gate rows). Weights
// (Whh0, Wih1, Whh1) as register A-frags, K split across 4 waves. Per phase:
// MFMA from rotating global h-buffers (normal cached loads, fresh slot per
// phase => never stale), pointwise, sc1-scoped h writes, fence-free barrier.
__global__ __launch_bounds__(256, 1) void k_recur(
    const float* __restrict__ W_ih, const float* __restrict__ W_hh,
    const float* __restrict__ h0_in, const float* __restrict__ c0_in,
    const __hip_bfloat16* __restrict__ Xbf,
    const __hip_bfloat16* __restrict__ XW0, const __hip_bfloat16* __restrict__ XW1,
    unsigned* __restrict__ h0f, unsigned* __restrict__ h1f,  // [66][8192] u32
    float* __restrict__ outs, float* __restrict__ out_states,
    unsigned* __restrict__ bar)
{
    __shared__ float red[2][4][2][16][17];   // [gateset][wave][ntile][row][col+pad]
    const int tid  = threadIdx.x;
    const int blk  = blockIdx.x;
    const int lane = tid & 63;
    const int w    = tid >> 6;
    const int r    = lane & 15, lg = lane >> 4;

    // ---- persistent weight A-frags: {Whh0, Wih1, Whh1}
    const int q = r >> 2, jl = r & 3;
    const int g = q * 512 + blk * 4 + jl;
    const float* Wm[3] = { W_hh, W_ih + (size_t)G_ * H_, W_hh + (size_t)G_ * H_ };
    bf16x8 wf[3][4];
#pragma unroll
    for (int m = 0; m < 3; m++)
#pragma unroll
        for (int s = 0; s < 4; s++) {
            const float* src = Wm[m] + (size_t)g * H_ + w * 128 + s * 32 + lg * 8;
            union { bf16x8 v; __hip_bfloat16 h[8]; } u;
#pragma unroll
            for (int e = 0; e < 8; e++) u.h[e] = __float2bfloat16(src[e]);
            wf[m][s] = u.v;
        }

    // ---- pointwise-owner state (tid<128): (b, pjl) -> j = blk*4+pjl
    const int b = tid & 31, pjl = (tid >> 5) & 3, pj = blk * 4 + pjl;
    // u32 slot for the (pj&~1, pj|1) bf16 pair at batch b
    const unsigned uoff = ((unsigned)(pj >> 3) * 32u + (unsigned)b) * 4u + (unsigned)((pj & 7) >> 1);
    float c0r = 0.f, c1r = 0.f, i1r = 0.f, h0l = 0.f, h1l = 0.f;
    if (tid < 128) {
        c0r = c0_in[b * H_ + pj];
        c1r = c0_in[B_ * H_ + b * H_ + pj];
        unsigned short m0 = bf16b(h0_in[b * H_ + pj]);
        unsigned short m1 = bf16b(h0_in[B_ * H_ + b * H_ + pj]);
        unsigned o0 = (unsigned)(unsigned short)__shfl_xor((int)m0, 32);
        unsigned o1 = (unsigned)(unsigned short)__shfl_xor((int)m1, 32);
        if (!(pjl & 1)) {
            // slot 0 (h0, read at phase 0) and slot 1 (h1, read at phase 1)
            __hip_atomic_store(h0f + 0 * 8192 + uoff, (unsigned)m0 | (o0 << 16),
                               __ATOMIC_RELAXED, __HIP_MEMORY_SCOPE_AGENT);
            __hip_atomic_store(h1f + 1 * 8192 + uoff, (unsigned)m1 | (o1 << 16),
                               __ATOMIC_RELAXED, __HIP_MEMORY_SCOPE_AGENT);
        }
    }

    // ---- fence-free grid barrier (syncthreads drains vmcnt before arrival)
    auto gbar = [&](int idx) {
        __syncthreads();
        if (tid == 0) {
            __hip_atomic_fetch_add(bar, 1u, __ATOMIC_RELAXED, __HIP_MEMORY_SCOPE_AGENT);
            unsigned tgt = (unsigned)NBLK * (unsigned)(idx + 1);
            while (__hip_atomic_load(bar, __ATOMIC_RELAXED, __HIP_MEMORY_SCOPE_AGENT) < tgt)
                __builtin_amdgcn_s_sleep(2);
        }
        __syncthreads();
    };

    gbar(0);

    for (int p = 0; p <= 64; ++p) {
        // ======== MFMA: gates from rotating h-buffers (slot p) ========
        const __hip_bfloat16* hb0 = (const __hip_bfloat16*)(h0f + (size_t)p * 8192);
        const __hip_bfloat16* hb1 = (const __hip_bfloat16*)(h1f + (size_t)p * 8192);
        f32x4 acc0[2] = {}, acc1[2] = {};
#pragma unroll
        for (int nt = 0; nt < 2; nt++)
#pragma unroll
            for (int s = 0; s < 4; s++) {
                int kq = w * 16 + s * 4 + lg;
                int ei = (kq * 32 + nt * 16 + r) << 3;
                bf16x8 bh0 = *(const bf16x8*)(hb0 + ei);
                bf16x8 bh1 = *(const bf16x8*)(hb1 + ei);
                if (p <= 63)
                    acc0[nt] = __builtin_amdgcn_mfma_f32_16x16x32_bf16(wf[0][s], bh0, acc0[nt], 0, 0, 0);
                if (p >= 1) {
                    acc1[nt] = __builtin_amdgcn_mfma_f32_16x16x32_bf16(wf[1][s], bh0, acc1[nt], 0, 0, 0);
                    acc1[nt] = __builtin_amdgcn_mfma_f32_16x16x32_bf16(wf[2][s], bh1, acc1[nt], 0, 0, 0);
                }
            }
#pragma unroll
        for (int nt = 0; nt < 2; nt++)
#pragma unroll
            for (int rr = 0; rr < 4; rr++) {
                red[0][w][nt][lg * 4 + rr][r] = acc0[nt][rr];
                red[1][w][nt][lg * 4 + rr][r] = acc1[nt][rr];
            }
        __syncthreads();

        // ======== pointwise (tid<128) ========
        if (tid < 128) {
            const int nt = b >> 4, col = b & 15;
            if (p >= 1) {                        // layer1 step t1 = p-1
                int t1 = p - 1;
                float gv[4];
#pragma unroll
                for (int qq = 0; qq < 4; qq++) {
                    float s = __bfloat162float(XW1[(size_t)(b * T_ + t1) * G_ + qq * 512 + pj]);
#pragma unroll
                    for (int ww = 0; ww < 4; ww++) s += red[1][ww][nt][qq * 4 + pjl][col];
                    gv[qq] = s;
                }
                float iv = sigm(gv[0]), fv = sigm(gv[1]);
                float gg = tanhf(gv[2]), ov = sigm(gv[3]);
                c1r = fv * c1r + iv * gg;
                float h1n = ov * tanhf(c1r);
                outs[((size_t)b * T_ + t1) * H_ + pj] = h1n + i1r;
                unsigned short mb = bf16b(h1n);
                unsigned ob = (unsigned)(unsigned short)__shfl_xor((int)mb, 32);
                if (!(pjl & 1))
                    __hip_atomic_store(h1f + (size_t)(p + 1) * 8192 + uoff,
                                       (unsigned)mb | (ob << 16),
                                       __ATOMIC_RELAXED, __HIP_MEMORY_SCOPE_AGENT);
                h1l = h1n;
            }
            if (p <= 63) {                       // layer0 step t0 = p
                float gv[4];
#pragma unroll
                for (int qq = 0; qq < 4; qq++) {
                    float s = __bfloat162float(XW0[(size_t)(b * T_ + p) * G_ + qq * 512 + pj]);
#pragma unroll
                    for (int ww = 0; ww < 4; ww++) s += red[0][ww][nt][qq * 4 + pjl][col];
                    gv[qq] = s;
                }
                float iv = sigm(gv[0]), fv = sigm(gv[1]);
                float gg = tanhf(gv[2]), ov = sigm(gv[3]);
                c0r = fv * c0r + iv * gg;
                float h0n = ov * tanhf(c0r);
                i1r = h0n + __bfloat162float(Xbf[(size_t)(b * T_ + p) * H_ + pj]);
                unsigned short mb = bf16b(h0n);
                unsigned ob = (unsigned)(unsigned short)__shfl_xor((int)mb, 32);
                if (!(pjl & 1))
                    __hip_atomic_store(h0f + (size_t)(p + 1) * 8192 + uoff,
                                       (unsigned)mb | (ob << 16),
                                       __ATOMIC_RELAXED, __HIP_MEMORY_SCOPE_AGENT);
                h0l = h0n;
            }
        }
        gbar(p + 1);
    }

    // ---- final hT/cT
    if (tid < 128) {
        out_states[b * H_ + pj]               = h0l;
        out_states[B_ * H_ + b * H_ + pj]     = h1l;
        out_states[2 * B_ * H_ + b * H_ + pj] = c0r;
        out_states[3 * B_ * H_ + b * H_ + pj] = c1r;
    }
}

// ---------------- bf16 NT MFMA GEMM: C = A[M,K]*B[N,K]^T + bias -------------
// 128x128 tile, BK=64, 4 waves, XOR-swizzled LDS, LDS-staged coalesced
// epilogue, XCD-chunked swizzle. Output fp32 (C) or bf16 (Cb) per pointer.
__global__ __launch_bounds__(256) void k_gemm_bf16nt(
    const __hip_bfloat16* __restrict__ A,
    const __hip_bfloat16* __restrict__ Bm,
    const float* __restrict__ bias,
    float* __restrict__ C, __hip_bfloat16* __restrict__ Cb,
    int K, int ldc, int nM)
{
    __shared__ char smem[64 * 130 * 4];        // sA|sB alias cbuf
    __hip_bfloat16* sA = (__hip_bfloat16*)smem;
    __hip_bfloat16* sB = (__hip_bfloat16*)(smem + 16384);
    float*          cbuf = (float*)smem;       // 64 x stride 130 fp32

    const int tid  = threadIdx.x;
    const int lane = tid & 63;
    const int wave = tid >> 6;
    const int wr = wave >> 1, wc = wave & 1;

    const int cpx = gridDim.x >> 3;
    const int gid = (blockIdx.x & 7) * cpx + (blockIdx.x >> 3);
    const int tm = gid % nM, tn = gid / nM;
    const size_t rowA0 = (size_t)tm * 128, rowB0 = (size_t)tn * 128;

    f32x4 acc[4][4] = {};

    for (int kt = 0; kt < K; kt += 64) {
        uint4 ra[4], rb[4];
#pragma unroll
        for (int i = 0; i < 4; i++) {
            int cid = i * 256 + tid;
            int rr = cid >> 3, c = cid & 7;
            ra[i] = *(const uint4*)(A  + (rowA0 + rr) * K + kt + c * 8);
            rb[i] = *(const uint4*)(Bm + (rowB0 + rr) * K + kt + c * 8);
        }
        __syncthreads();
#pragma unroll
        for (int i = 0; i < 4; i++) {
            int cid = i * 256 + tid;
            int rr = cid >> 3, c = cid & 7;
            int cd = c ^ (rr & 7);
            *(uint4*)((char*)sA + rr * 128 + cd * 16) = ra[i];
            *(uint4*)((char*)sB + rr * 128 + cd * 16) = rb[i];
        }
        __syncthreads();
#pragma unroll
        for (int kk = 0; kk < 2; kk++) {
            bf16x8 af[4], bfr[4];
            int kc = kk * 4 + (lane >> 4);
#pragma unroll
            for (int mi = 0; mi < 4; mi++) {
                int rr = wr * 64 + mi * 16 + (lane & 15);
                af[mi] = *(const bf16x8*)((const char*)sA + rr * 128 + ((kc ^ (rr & 7)) << 4));
            }
#pragma unroll
            for (int ni = 0; ni < 4; ni++) {
                int rr = wc * 64 + ni * 16 + (lane & 15);
                bfr[ni] = *(const bf16x8*)((const char*)sB + rr * 128 + ((kc ^ (rr & 7)) << 4));
            }
#pragma unroll
            for (int mi = 0; mi < 4; mi++)
#pragma unroll
                for (int ni = 0; ni < 4; ni++)
                    acc[mi][ni] = __builtin_amdgcn_mfma_f32_16x16x32_bf16(af[mi], bfr[ni], acc[mi][ni], 0, 0, 0);
        }
    }

    // epilogue: stage 64-row halves in LDS, store full lines
#pragma unroll
    for (int half = 0; half < 2; half++) {
        __syncthreads();
        if (wr == half) {
#pragma unroll
            for (int mi = 0; mi < 4; mi++)
#pragma unroll
                for (int ni = 0; ni < 4; ni++)
#pragma unroll
                    for (int rr = 0; rr < 4; rr++)
                        cbuf[(mi * 16 + ((lane >> 4)) * 4 + rr) * 130 + wc * 64 + ni * 16 + (lane & 15)] = acc[mi][ni][rr];
        }
        __syncthreads();
        int c4 = (tid & 31) * 4;
        float4 bb = *(const float4*)(bias + rowB0 + c4);
#pragma unroll
        for (int it = 0; it < 8; it++) {
            int rrow = it * 8 + (tid >> 5);
            float4 vv = *(float4*)(cbuf + rrow * 130 + c4);
            vv.x += bb.x; vv.y += bb.y; vv.z += bb.z; vv.w += bb.w;
            size_t orow = (size_t)(rowA0 + half * 64 + rrow);
            if (Cb) {
                ushort4 pv;
                pv.x = bf16b(vv.x); pv.y = bf16b(vv.y);
                pv.z = bf16b(vv.z); pv.w = bf16b(vv.w);
                *(ushort4*)(Cb + orow * ldc + rowB0 + c4) = pv;
            } else {
                *(float4*)(C + orow * ldc + rowB0 + c4) = vv;
            }
        }
    }
}

// ---------------- attention (all B*T rows), writes bf16 A-operand ----------
__global__ __launch_bounds__(256) void k_attn(const float* __restrict__ context,
                                              const float* __restrict__ outs,
                                              __hip_bfloat16* __restrict__ ctxbf)
{
    __shared__ float orow[512];
    __shared__ float sc2[128][2];
    __shared__ float la[128];
    const int m = blockIdx.x;         // b*T + t
    const int b = m >> 6;
    const float* ctxb = context + (size_t)b * S_ * H_;
    const int tid = threadIdx.x;
    orow[tid]       = outs[(size_t)m * H_ + tid];
    orow[tid + 256] = outs[(size_t)m * H_ + tid + 256];
    __syncthreads();
    {
        int s = tid >> 1, p = tid & 1;
        const float4* crow = (const float4*)(ctxb + (size_t)s * H_ + p * 256);
        const float4* orp  = (const float4*)(orow + p * 256);
        float acc = 0.f;
#pragma unroll 4
        for (int k = 0; k < 64; k++) {
            float4 cv = crow[k]; float4 ov = orp[k];
            acc = fmaf(cv.x, ov.x, fmaf(cv.y, ov.y, fmaf(cv.z, ov.z, fmaf(cv.w, ov.w, acc))));
        }
        sc2[s][p] = acc;
    }
    __syncthreads();
    if (tid < 64) {
        float a  = sc2[tid][0] + sc2[tid][1];
        float b2 = sc2[tid + 64][0] + sc2[tid + 64][1];
        float mx = fmaxf(a, b2);
#pragma unroll
        for (int off = 32; off >= 1; off >>= 1) mx = fmaxf(mx, __shfl_xor(mx, off, 64));
        float es = expf(a - mx) + expf(b2 - mx);
#pragma unroll
        for (int off = 32; off >= 1; off >>= 1) es += __shfl_xor(es, off, 64);
        float lse = mx + logf(es);
        la[tid]      = a  - lse;
        la[tid + 64] = b2 - lse;
    }
    __syncthreads();
    {
        float a0 = 0.f, a1 = 0.f;
        for (int s2 = 0; s2 < 128; s2++) {
            float w = la[s2];
            a0 = fmaf(ctxb[(size_t)s2 * H_ + tid], w, a0);
            a1 = fmaf(ctxb[(size_t)s2 * H_ + tid + 256], w, a1);
        }
        ctxbf[(size_t)m * H_ + tid]       = __float2bfloat16(a0);
        ctxbf[(size_t)m * H_ + tid + 256] = __float2bfloat16(a1);
    }
}

extern "C" void kernel_launch(void* const* d_in, const int* in_sizes, int n_in,
                              void* d_out, int out_size, void* d_ws, size_t ws_size,
                              hipStream_t stream)
{
    const float* context = (const float*)d_in[0];
    const int*   dec     = (const int*)d_in[1];
    const float* h0      = (const float*)d_in[2];
    const float* c0      = (const float*)d_in[3];
    const float* emb     = (const float*)d_in[4];
    const float* W_ih    = (const float*)d_in[5];
    const float* W_hh    = (const float*)d_in[6];
    const float* b_ih    = (const float*)d_in[7];
    const float* b_hh    = (const float*)d_in[8];
    const float* Wc      = (const float*)d_in[9];
    const float* bc      = (const float*)d_in[10];
    float* out = (float*)d_out;

    char* ws = (char*)d_ws;
    size_t off = 0;
    auto alloc = [&](size_t bytes) -> char* {
        char* p = ws + off; off += (bytes + 255) & ~(size_t)255; return p;
    };
    __hip_bfloat16* Xbf    = (__hip_bfloat16*)alloc((size_t)B_ * T_ * H_ * 2);
    __hip_bfloat16* Wihbf  = (__hip_bfloat16*)alloc((size_t)2 * G_ * H_ * 2);
    __hip_bfloat16* Wcbf   = (__hip_bfloat16*)alloc((size_t)V_ * H_ * 2);
    __hip_bfloat16* XW0    = (__hip_bfloat16*)alloc((size_t)B_ * T_ * G_ * 2);
    __hip_bfloat16* XW1    = (__hip_bfloat16*)alloc((size_t)B_ * T_ * G_ * 2);
    float*          bias0  = (float*)alloc(G_ * 4);
    float*          bias1  = (float*)alloc(G_ * 4);
    unsigned*       h0f    = (unsigned*)alloc((size_t)66 * 8192 * 4);
    unsigned*       h1f    = (unsigned*)alloc((size_t)66 * 8192 * 4);
    float*          outs   = (float*)alloc((size_t)B_ * T_ * H_ * 4);
    __hip_bfloat16* ctxbf  = (__hip_bfloat16*)alloc((size_t)B_ * T_ * H_ * 2);
    unsigned*       bar    = (unsigned*)alloc(256);

    hipMemsetAsync(bar, 0, 256, stream);

    // prep
    k_embed<<<(B_ * T_ * H_ / 4) / 256, 256, 0, stream>>>(dec, emb, Xbf);
    k_f2bf<<<(2 * G_ * H_ / 4) / 256, 256, 0, stream>>>(W_ih, Wihbf, 2 * G_ * H_ / 4);
    k_f2bf<<<(V_ * H_ / 4) / 256, 256, 0, stream>>>(Wc, Wcbf, V_ * H_ / 4);
    k_prep<<<G_ / 256, 256, 0, stream>>>(b_ih, b_hh, bias0, bias1);

    // XW_l = X @ Wih_l^T + bias_l  -> bf16 [2048, 2048]
    k_gemm_bf16nt<<<16 * 16, 256, 0, stream>>>(Xbf, Wihbf, bias0, nullptr, XW0, H_, G_, 16);
    k_gemm_bf16nt<<<16 * 16, 256, 0, stream>>>(Xbf, Wihbf + (size_t)G_ * H_, bias1, nullptr, XW1, H_, G_, 16);

    // persistent fused recurrence
    k_recur<<<NBLK, 256, 0, stream>>>(W_ih, W_hh, h0, c0, Xbf, XW0, XW1,
                                      h0f, h1f, outs, out + (size_t)B_ * T_ * V_, bar);

    // attention -> bf16 ctx vectors
    k_attn<<<B_ * T_, 256, 0, stream>>>(context, outs, ctxbf);

    // logits = ctx @ Wc^T + bc  [2048, 32000] fp32 into d_out
    k_gemm_bf16nt<<<(V_ / 128) * ((B_ * T_) / 128), 256, 0, stream>>>(
        ctxbf, Wcbf, bc, out, nullptr, H_, V_, (B_ * T_) / 128);
}